// Round 7
// baseline (153.585 us; speedup 1.0000x reference)
//
#include <hip/hip_runtime.h>

#define BTOT 8192
#define TT 512
#define LOG2E 1.44269504089f

__device__ __forceinline__ float bperm(int addr4, float v) {
    return __int_as_float(__builtin_amdgcn_ds_bpermute(addr4, __float_as_int(v)));
}
template<int CTRL>
__device__ __forceinline__ float qb(float v) {   // quad_perm broadcast
    return __int_as_float(__builtin_amdgcn_mov_dpp(__float_as_int(v), CTRL, 0xf, 0xf, true));
}

// 2^t on the VALU: split t = n + f, e^{f ln2} via 5-term Taylor (err <= 2e-4 rel,
// exact bound: (ln2)^6/720 ~ 1.5e-4), then ldexp. Clamped to |t|<=30 so the
// downstream 1/(1+E) bit-trick stays in normal-float range.
__device__ __forceinline__ float soft_exp2(float t) {
    t = __builtin_amdgcn_fmed3f(t, -30.0f, 30.0f);
    const float n = floorf(t);
    const float f = t - n;
    float p = fmaf(f, 0.0013333558f, 0.0096181291f);   // ln2^5/120, ln2^4/24
    p = fmaf(p, f, 0.0555041087f);                      // ln2^3/6
    p = fmaf(p, f, 0.2402265070f);                      // ln2^2/2
    p = fmaf(p, f, 0.6931471806f);                      // ln2
    p = fmaf(p, f, 1.0f);
    return ldexpf(p, (int)n);
}

// 1/(1+E) on the VALU, E in [2^-30, 2^31] guaranteed by soft_exp2's clamp.
// d = m*2^e, seed r0 = 48/17 - 32/17*(m/2) on m in [1,2), 2 Newton steps:
// rel err (1/17)^4 ~ 1.2e-5.
__device__ __forceinline__ float soft_rcp1p(float E) {
    const float d = 1.0f + E;
    const int bi = __float_as_int(d);
    const int e  = (bi >> 23) - 127;                         // 0..31
    const float m = __int_as_float((bi & 0x007FFFFF) | 0x3F800000);  // [1,2)
    float r = fmaf(m, -0.47058824f, 1.41176471f);
    r = r * fmaf(-m, r, 2.0f);
    r = r * fmaf(-m, r, 2.0f);
    return __int_as_float(__float_as_int(r) - (e << 23));
}

__global__ __launch_bounds__(64) void lstm_kernel(
    const float* __restrict__ x,
    const float* __restrict__ W_ih,
    const float* __restrict__ W_hh,
    const float* __restrict__ b_ih,
    const float* __restrict__ b_hh,
    const float* __restrict__ fc1_w,
    const float* __restrict__ fc1_b,
    const float* __restrict__ fc2_w,
    const float* __restrict__ fc2_b,
    float* __restrict__ out)
{
    // mild phase stagger to de-convoy co-resident waves (uniform per wave)
    switch (blockIdx.x & 3) {
        case 1: __builtin_amdgcn_s_sleep(2); break;
        case 2: __builtin_amdgcn_s_sleep(4); break;
        case 3: __builtin_amdgcn_s_sleep(6); break;
        default: break;
    }

    const int lane   = threadIdx.x;                 // one wave per block
    const int ll     = (lane < 60) ? lane : 59;     // idle lanes alias lane 59
    const int bw     = ll / 20;                     // batch within wave: 0..2
    const int within = ll % 20;                     // row slot within batch group
    const int j      = within >> 2;                 // hidden unit (quad index, 0..4)
    const int g      = within & 3;                  // gate (0=i,1=f,2=g,3=o)
    const int base   = bw * 20;                     // group base lane (0/20/40, 4-aligned)
    const int b_raw  = blockIdx.x * 3 + bw;
    const bool write_ok = (lane < 60) && (within == 0) && (b_raw < BTOT);
    const int b = (b_raw < BTOT) ? b_raw : (BTOT - 1);

    // i,f,o: acc = -z*log2e -> sigmoid(z) = soft_rcp1p(soft_exp2(acc)); val = r
    // g    : acc = 2z*log2e -> tanh(z) = 1-2r; val = 2L*tanh(z) = fma(-4L, r, 2L)
    //        (pre-scaled so the cell accumulates C = 2L*c, feeding exp2 directly)
    const float sc   = (g == 2) ? (2.0f * LOG2E) : (-LOG2E);
    const float selA = (g == 2) ? (-4.0f * LOG2E) : 1.0f;
    const float selB = (g == 2) ? ( 2.0f * LOG2E) : 0.0f;

    const int row = g * 5 + j;                      // PyTorch gate-major row
    float wih[5], whh[5];
    #pragma unroll
    for (int i = 0; i < 5; ++i) {
        wih[i] = sc * W_ih[row * 5 + i];
        whh[i] = sc * W_hh[row * 5 + i];
    }
    const float bias_s = sc * (b_ih[row] + b_hh[row]);

    // h_k replicated across quad k; gather from quad-base lanes
    int a_h[5];
    #pragma unroll
    for (int k = 0; k < 5; ++k) a_h[k] = (base + 4 * k) << 2;

    const float* xb = x + (size_t)b * (TT * 5);

    float hv[5] = {0.f, 0.f, 0.f, 0.f, 0.f};
    float C = 0.f;                                   // 2*log2e * c

    float4 bufA[5], bufB[5];
    #pragma unroll
    for (int i = 0; i < 5; ++i) {
        bufA[i] = *(const float4*)(xb + 0  + 4 * i);   // t = 0..3
        bufB[i] = *(const float4*)(xb + 20 + 4 * i);   // t = 4..7
    }

    auto process4 = [&](const float4* buf) {
        float xs[20];
        *(float4*)&xs[0]  = buf[0];
        *(float4*)&xs[4]  = buf[1];
        *(float4*)&xs[8]  = buf[2];
        *(float4*)&xs[12] = buf[3];
        *(float4*)&xs[16] = buf[4];

        auto proj = [&](int s) {
            float a = bias_s;
            #pragma unroll
            for (int i = 0; i < 5; ++i) a = fmaf(wih[i], xs[s * 5 + i], a);
            return a;
        };

        float gxc = proj(0);
        #pragma unroll
        for (int s = 0; s < 4; ++s) {
            // own row's recurrent dot + activation (all-VALU)
            float acc = gxc;
            #pragma unroll
            for (int k = 0; k < 5; ++k) acc = fmaf(whh[k], hv[k], acc);
            const float r1  = soft_rcp1p(soft_exp2(acc));
            const float val = fmaf(selA, r1, selB);

            // unit j's 4 gates live in this quad
            const float iv = qb<0x00>(val);
            const float fv = qb<0x55>(val);
            const float gv = qb<0xAA>(val);   // already 2L-scaled
            const float ov = qb<0xFF>(val);

            // cell update (C = 2L*c), tanh(c) = 1 - 2/(1+2^C)
            C = fmaf(fv, C, iv * gv);
            const float r2 = soft_rcp1p(soft_exp2(C));
            const float h  = ov * fmaf(-2.0f, r2, 1.0f);

            // single LDS round: gather h_0..h_4 from quad-base lanes
            #pragma unroll
            for (int k = 0; k < 5; ++k) hv[k] = bperm(a_h[k], h);

            // fill the bperm shadow with next step's x-projection
            if (s < 3) gxc = proj(s + 1);
        }
    };

    for (int t0 = 0; t0 < TT; t0 += 8) {
        process4(bufA);                                // steps t0 .. t0+3
        {
            const int tld = (t0 + 8 <= TT - 4) ? (t0 + 8) : (TT - 4);
            const float* p = xb + tld * 5;
            #pragma unroll
            for (int i = 0; i < 5; ++i) bufA[i] = *(const float4*)(p + 4 * i);
        }
        process4(bufB);                                // steps t0+4 .. t0+7
        {
            const int tld = (t0 + 12 <= TT - 4) ? (t0 + 12) : (TT - 4);
            const float* p = xb + tld * 5;
            #pragma unroll
            for (int i = 0; i < 5; ++i) bufB[i] = *(const float4*)(p + 4 * i);
        }
    }

    // hv holds the final hidden state on every lane
    if (write_ok) {
        float p = fc1_b[0];
        float v = fc2_b[0];
        #pragma unroll
        for (int k = 0; k < 5; ++k) {
            p = fmaf(fc1_w[k], hv[k], p);
            v = fmaf(fc2_w[k], hv[k], v);
        }
        out[b] = p;
        out[BTOT + b] = v;
    }
}

extern "C" void kernel_launch(void* const* d_in, const int* in_sizes, int n_in,
                              void* d_out, int out_size, void* d_ws, size_t ws_size,
                              hipStream_t stream) {
    const float* x     = (const float*)d_in[0];
    const float* W_ih  = (const float*)d_in[1];
    const float* W_hh  = (const float*)d_in[2];
    const float* b_ih  = (const float*)d_in[3];
    const float* b_hh  = (const float*)d_in[4];
    const float* fc1_w = (const float*)d_in[5];
    const float* fc1_b = (const float*)d_in[6];
    const float* fc2_w = (const float*)d_in[7];
    const float* fc2_b = (const float*)d_in[8];
    float* out = (float*)d_out;

    const int blocks = (BTOT + 2) / 3;   // 2731 one-wave blocks, 3 batches each
    lstm_kernel<<<blocks, 64, 0, stream>>>(x, W_ih, W_hh, b_ih, b_hh,
                                           fc1_w, fc1_b, fc2_w, fc2_b, out);
}

// Round 8
// 150.792 us; speedup vs baseline: 1.0185x; 1.0185x over previous
//
#include <hip/hip_runtime.h>

#define BTOT 8192
#define TT 512

__device__ __forceinline__ float bperm(int addr4, float v) {
    return __int_as_float(__builtin_amdgcn_ds_bpermute(addr4, __float_as_int(v)));
}
template<int CTRL>
__device__ __forceinline__ float qb(float v) {   // quad_perm broadcast
    return __int_as_float(__builtin_amdgcn_mov_dpp(__float_as_int(v), CTRL, 0xf, 0xf, true));
}

// soft reciprocal: magic-constant seed (~5% err) + 2 Newton -> ~6e-6 rel.
// depth ~40 cy vs v_rcp_f32's ~100 cy dep latency. d > 0 guaranteed here.
__device__ __forceinline__ float srcp(float d) {
    float r = __int_as_float(0x7EF311C3 - __float_as_int(d));
    r = r * fmaf(-d, r, 2.0f);
    r = r * fmaf(-d, r, 2.0f);
    return r;
}

// tanh Pade (CF depth 7): tanh(t) ~ t*(135135+17325u+378u^2+u^3) /
//                                    (135135+62370u+3150u^2+28u^3),  u=t^2
// verified: err <= ~2e-5 on [-4,4], ~1e-4 at clamp edge |t|=5 (tanh(5)=0.99991).
// num_p / den evaluated as parallel Horner chains (depth ~3 fma).
__device__ __forceinline__ void tanh_parts(float t, float& num, float& den) {
    const float u = t * t;
    float np = u + 378.0f;
    np = fmaf(np, u, 17325.0f);
    np = fmaf(np, u, 135135.0f);
    num = t * np;
    float dp = fmaf(28.0f, u, 3150.0f);
    dp = fmaf(dp, u, 62370.0f);
    den = fmaf(dp, u, 135135.0f);
}

__global__ __launch_bounds__(64) void lstm_kernel(
    const float* __restrict__ x,
    const float* __restrict__ W_ih,
    const float* __restrict__ W_hh,
    const float* __restrict__ b_ih,
    const float* __restrict__ b_hh,
    const float* __restrict__ fc1_w,
    const float* __restrict__ fc1_b,
    const float* __restrict__ fc2_w,
    const float* __restrict__ fc2_b,
    float* __restrict__ out)
{
    const int lane   = threadIdx.x;                 // one wave per block
    const int ll     = (lane < 60) ? lane : 59;     // idle lanes alias lane 59
    const int bw     = ll / 20;                     // batch within wave: 0..2
    const int within = ll % 20;                     // row slot within batch group
    const int j      = within >> 2;                 // hidden unit (quad index, 0..4)
    const int g      = within & 3;                  // gate (0=i,1=f,2=g,3=o)
    const int base   = bw * 20;                     // group base lane (0/20/40, 4-aligned)
    const int b_raw  = blockIdx.x * 3 + bw;
    const bool write_ok = (lane < 60) && (within == 0) && (b_raw < BTOT);
    const int b = (b_raw < BTOT) ? b_raw : (BTOT - 1);

    // sigmoid(z) = 0.5 + 0.5*tanh(z/2): fold the /2 into the weights for i,f,o.
    // g-gate keeps scale 1 and takes tanh directly.
    //   val = (selA*num + selB*den) * srcp(den)
    //   i,f,o: selA=selB=0.5  -> 0.5*(num+den)/den = sigmoid(z)
    //   g    : selA=1, selB=0 -> num/den           = tanh(z)
    const float sc   = (g == 2) ? 1.0f : 0.5f;
    const float selA = (g == 2) ? 1.0f : 0.5f;
    const float selB = (g == 2) ? 0.0f : 0.5f;

    const int row = g * 5 + j;                      // PyTorch gate-major row
    float wih[5], whh[5];
    #pragma unroll
    for (int i = 0; i < 5; ++i) {
        wih[i] = sc * W_ih[row * 5 + i];
        whh[i] = sc * W_hh[row * 5 + i];
    }
    const float bias_s = sc * (b_ih[row] + b_hh[row]);

    // h_j replicated across quad j; gather from quad-base lanes
    int a_h[5];
    #pragma unroll
    for (int k = 0; k < 5; ++k) a_h[k] = (base + 4 * k) << 2;

    const float* xb = x + (size_t)b * (TT * 5);

    float hv[5] = {0.f, 0.f, 0.f, 0.f, 0.f};
    float C = 0.f;                                   // cell state

    float4 bufA[5], bufB[5];
    #pragma unroll
    for (int i = 0; i < 5; ++i) {
        bufA[i] = *(const float4*)(xb + 0  + 4 * i);   // t = 0..3
        bufB[i] = *(const float4*)(xb + 20 + 4 * i);   // t = 4..7
    }

    auto process4 = [&](const float4* buf) {
        float xs[20];
        *(float4*)&xs[0]  = buf[0];
        *(float4*)&xs[4]  = buf[1];
        *(float4*)&xs[8]  = buf[2];
        *(float4*)&xs[12] = buf[3];
        *(float4*)&xs[16] = buf[4];

        auto proj = [&](int s) {
            float a = bias_s;
            #pragma unroll
            for (int i = 0; i < 5; ++i) a = fmaf(wih[i], xs[s * 5 + i], a);
            return a;
        };

        float gxc = proj(0);
        #pragma unroll
        for (int s = 0; s < 4; ++s) {
            // recurrent dot as a tree (shorter dep chain than serial fma)
            const float m0 = whh[0] * hv[0];
            const float m1 = whh[1] * hv[1];
            const float m2 = whh[2] * hv[2];
            const float m3 = whh[3] * hv[3];
            const float m4 = whh[4] * hv[4];
            const float a01 = m0 + m1;
            const float a23 = m2 + m3;
            const float a4g = m4 + gxc;
            const float acc = (a01 + a23) + a4g;

            // activation via Pade rational (all-VALU, depth ~95)
            const float t1 = __builtin_amdgcn_fmed3f(acc, -5.0f, 5.0f);
            float num1, den1;
            tanh_parts(t1, num1, den1);
            const float r1  = srcp(den1);
            const float pre = fmaf(selA, num1, selB * den1);
            const float val = pre * r1;

            // unit j's 4 gates live in this quad: 4 DPP broadcasts
            const float iv = qb<0x00>(val);
            const float fv = qb<0x55>(val);
            const float gv = qb<0xAA>(val);
            const float ov = qb<0xFF>(val);

            // cell update + tanh(C) via the same rational
            C = fmaf(fv, C, iv * gv);
            const float t2 = __builtin_amdgcn_fmed3f(C, -5.0f, 5.0f);
            float num2, den2;
            tanh_parts(t2, num2, den2);
            const float tc = num2 * srcp(den2);
            const float h  = ov * tc;

            // single LDS round: gather h_0..h_4 from quad-base lanes
            #pragma unroll
            for (int k = 0; k < 5; ++k) hv[k] = bperm(a_h[k], h);

            // fill the bperm shadow with next step's x-projection
            if (s < 3) gxc = proj(s + 1);
        }
    };

    for (int t0 = 0; t0 < TT; t0 += 8) {
        process4(bufA);                                // steps t0 .. t0+3
        {
            const int tld = (t0 + 8 <= TT - 4) ? (t0 + 8) : (TT - 4);
            const float* p = xb + tld * 5;
            #pragma unroll
            for (int i = 0; i < 5; ++i) bufA[i] = *(const float4*)(p + 4 * i);
        }
        process4(bufB);                                // steps t0+4 .. t0+7
        {
            const int tld = (t0 + 12 <= TT - 4) ? (t0 + 12) : (TT - 4);
            const float* p = xb + tld * 5;
            #pragma unroll
            for (int i = 0; i < 5; ++i) bufB[i] = *(const float4*)(p + 4 * i);
        }
    }

    // hv holds the final hidden state on every lane
    if (write_ok) {
        float p = fc1_b[0];
        float v = fc2_b[0];
        #pragma unroll
        for (int k = 0; k < 5; ++k) {
            p = fmaf(fc1_w[k], hv[k], p);
            v = fmaf(fc2_w[k], hv[k], v);
        }
        out[b] = p;
        out[BTOT + b] = v;
    }
}

extern "C" void kernel_launch(void* const* d_in, const int* in_sizes, int n_in,
                              void* d_out, int out_size, void* d_ws, size_t ws_size,
                              hipStream_t stream) {
    const float* x     = (const float*)d_in[0];
    const float* W_ih  = (const float*)d_in[1];
    const float* W_hh  = (const float*)d_in[2];
    const float* b_ih  = (const float*)d_in[3];
    const float* b_hh  = (const float*)d_in[4];
    const float* fc1_w = (const float*)d_in[5];
    const float* fc1_b = (const float*)d_in[6];
    const float* fc2_w = (const float*)d_in[7];
    const float* fc2_b = (const float*)d_in[8];
    float* out = (float*)d_out;

    const int blocks = (BTOT + 2) / 3;   // 2731 one-wave blocks, 3 batches each
    lstm_kernel<<<blocks, 64, 0, stream>>>(x, W_ih, W_hh, b_ih, b_hh,
                                           fc1_w, fc1_b, fc2_w, fc2_b, out);
}